// Round 6
// baseline (464.534 us; speedup 1.0000x reference)
//
#include <hip/hip_runtime.h>
#include <cstdint>
#include <cstring>

typedef short short8 __attribute__((ext_vector_type(8)));
typedef float float4v __attribute__((ext_vector_type(4)));
typedef float float4g __attribute__((ext_vector_type(4)));
typedef unsigned short ushort4v __attribute__((ext_vector_type(4)));
typedef unsigned int uint2v __attribute__((ext_vector_type(2)));

typedef __attribute__((address_space(3))) unsigned int lds_uint;
typedef __attribute__((address_space(1))) const unsigned int glob_uint;

static __device__ __forceinline__ void async16(void* lds, const void* g) {
    __builtin_amdgcn_global_load_lds((glob_uint*)g, (lds_uint*)lds, 16, 0, 0);
}

static __device__ __forceinline__ float b2f(unsigned short u) {
    unsigned int x = ((unsigned int)u) << 16;
    float f;
    __builtin_memcpy(&f, &x, 4);
    return f;
}
static __device__ __forceinline__ unsigned short f2b(float f) {
    unsigned int x;
    __builtin_memcpy(&x, &f, 4);
    unsigned int r = (x + 0x7fffu + ((x >> 16) & 1u)) >> 16;
    return (unsigned short)r;
}

// ---------------- fused fp32 -> bf16 convert for all 6 tensors ----------------
// region block boundaries (each block = 1024 elems = 256 thr x 4):
// hs 8192 | wqa 3072 | wqb 4608 (scaled) | wkva 1152 | wkvb 2048 | wo 4096 => 23168
__global__ __launch_bounds__(256) void k_f2b6(
    const float* __restrict__ s0, unsigned short* __restrict__ d0,
    const float* __restrict__ s1, unsigned short* __restrict__ d1,
    const float* __restrict__ s2, unsigned short* __restrict__ d2,
    const float* __restrict__ s3, unsigned short* __restrict__ d3,
    const float* __restrict__ s4, unsigned short* __restrict__ d4,
    const float* __restrict__ s5, unsigned short* __restrict__ d5,
    float qs) {
    int blk = blockIdx.x;
    const float* s; unsigned short* d; float sc = 1.f; int rel;
    if (blk < 8192)       { s = s0; d = d0; rel = blk; }
    else if (blk < 11264) { s = s1; d = d1; rel = blk - 8192; }
    else if (blk < 15872) { s = s2; d = d2; rel = blk - 11264; sc = qs; }
    else if (blk < 17024) { s = s3; d = d3; rel = blk - 15872; }
    else if (blk < 19072) { s = s4; d = d4; rel = blk - 17024; }
    else                  { s = s5; d = d5; rel = blk - 19072; }
    int i = (rel * 256 + threadIdx.x) * 4;
    float4g v = *(const float4g*)(s + i);
    ushort4v r;
    r.x = f2b(v.x * sc); r.y = f2b(v.y * sc); r.z = f2b(v.z * sc); r.w = f2b(v.w * sc);
    *(ushort4v*)(d + i) = r;
}

// ---------------- bf16 GEMM body (m97 recipe): C[M,N] = A[M,K] @ W[N,K]^T ----------------
// mode: 0 = bf16 C, 1 = fp32 C, 2 = kvsplit (bf16 C for k_nope cols, V cols -> VT[bh][d][s])
static __device__ __forceinline__ void gemm_bt_body(
    const unsigned short* __restrict__ A, int lda,
    const unsigned short* __restrict__ W,
    void* __restrict__ C, int ldc,
    int N, int K, int mode, int bx, int by,
    unsigned short* __restrict__ VT) {
    __shared__ __align__(16) unsigned short As[128 * 32];
    __shared__ __align__(16) unsigned short Ws[128 * 32];
    const int tid = threadIdx.x;
    const int m0 = by * 128, n0 = bx * 128;
    const int wave = tid >> 6, lane = tid & 63;
    const int wm = (wave >> 1) * 64, wn = (wave & 1) * 64;
    const int lrow = lane & 15, quad = lane >> 4;
    const int srow = lane >> 2, spiece = lane & 3;

    float4v acc[4][4];
    float4v z = {0.f, 0.f, 0.f, 0.f};
#pragma unroll
    for (int i = 0; i < 4; i++)
#pragma unroll
        for (int j = 0; j < 4; j++) acc[i][j] = z;

    for (int k0 = 0; k0 < K; k0 += 32) {
#pragma unroll
        for (int ii = 0; ii < 2; ++ii) {
            int i = wave + ii * 4;
            int row = i * 16 + srow;
            async16(&As[i * 512], &A[(size_t)(m0 + row) * lda + k0 + spiece * 8]);
            int wr = n0 + row;
            if (wr > N - 1) wr = N - 1;
            async16(&Ws[i * 512], &W[(size_t)wr * K + k0 + spiece * 8]);
        }
        __syncthreads();
        short8 af[4], bfr[4];
#pragma unroll
        for (int i = 0; i < 4; i++)
            af[i] = *(const short8*)&As[(wm + i * 16 + lrow) * 32 + quad * 8];
#pragma unroll
        for (int i = 0; i < 4; i++)
            bfr[i] = *(const short8*)&Ws[(wn + i * 16 + lrow) * 32 + quad * 8];
#pragma unroll
        for (int i = 0; i < 4; i++)
#pragma unroll
            for (int j = 0; j < 4; j++)
                acc[i][j] = __builtin_amdgcn_mfma_f32_16x16x32_bf16(af[i], bfr[j], acc[i][j], 0, 0, 0);
        __syncthreads();
    }

    const int rbase = quad * 4;
#pragma unroll
    for (int i = 0; i < 4; i++) {
#pragma unroll
        for (int j = 0; j < 4; j++) {
            int col = n0 + wn + j * 16 + lrow;
            if (col >= N) continue;
            if (mode == 2) {
                // kvb output: col = h*256 + dd. dd<128 -> k_nope (kvbuf);
                // dd>=128 -> V, store transposed to VT[(b*16+h)][dd-128][s].
                int dd = col & 255, h = col >> 8;
#pragma unroll
                for (int r = 0; r < 4; r++) {
                    int row = m0 + wm + i * 16 + rbase + r;  // token
                    float v = acc[i][j][r];
                    if (dd < 128) {
                        ((unsigned short*)C)[(size_t)row * ldc + col] = f2b(v);
                    } else {
                        int b = row >> 11, s = row & 2047;
                        VT[((size_t)(b * 16 + h) * 128 + (dd - 128)) * 2048 + s] = f2b(v);
                    }
                }
            } else {
#pragma unroll
                for (int r = 0; r < 4; r++) {
                    int row = m0 + wm + i * 16 + rbase + r;
                    float v = acc[i][j][r];
                    if (mode == 1)
                        ((float*)C)[(size_t)row * ldc + col] = v;
                    else
                        ((unsigned short*)C)[(size_t)row * ldc + col] = f2b(v);
                }
            }
        }
    }
}

__global__ __launch_bounds__(256, 3)
void k_gemm_bt(const unsigned short* __restrict__ A, int lda,
               const unsigned short* __restrict__ W,
               void* __restrict__ C, int ldc,
               int N, int K, int mode) {
    gemm_bt_body(A, lda, W, C, ldc, N, K, mode, blockIdx.x, blockIdx.y, nullptr);
}

// Ganged dual-GEMM: blocks [0,nbx0) run problem 0 (bf16 out), rest problem 1
// (mode1: 0=bf16, 2=kvsplit with VT).
__global__ __launch_bounds__(256, 3)
void k_gemm_dual(const unsigned short* __restrict__ A0, int lda0,
                 const unsigned short* __restrict__ W0, void* __restrict__ C0,
                 int ldc0, int N0, int K0, int nbx0,
                 const unsigned short* __restrict__ A1, int lda1,
                 const unsigned short* __restrict__ W1, void* __restrict__ C1,
                 int ldc1, int N1, int K1, int mode1,
                 unsigned short* __restrict__ VT) {
    int bx = blockIdx.x;
    if (bx < nbx0) {
        gemm_bt_body(A0, lda0, W0, C0, ldc0, N0, K0, 0, bx, blockIdx.y, nullptr);
    } else {
        gemm_bt_body(A1, lda1, W1, C1, ldc1, N1, K1, mode1, bx - nbx0, blockIdx.y, VT);
    }
}

// ---------------- fused: rmsnorm(qa) | rmsnorm(ckv)+rope_k ----------------
// blocks 0..4095: qa row (1536 cols, 192 thr). blocks 4096..8191: ckv row
// (rmsnorm 512 cols on thr 0..63, rope_k cols 512..575 on thr 64..95).
__global__ __launch_bounds__(192) void k_norm2(
    unsigned short* __restrict__ qa, const float* __restrict__ g_qa,
    unsigned short* __restrict__ ckv, const float* __restrict__ g_kva) {
    __shared__ float wsum[3];
    int blk = blockIdx.x;
    int tid = threadIdx.x;
    if (blk < 4096) {
        size_t base = (size_t)blk * 1536 + tid * 8;
        short8 v8 = *(const short8*)(qa + base);
        float vf[8];
        float ss = 0.f;
#pragma unroll
        for (int i = 0; i < 8; i++) {
            vf[i] = b2f((unsigned short)v8[i]);
            ss += vf[i] * vf[i];
        }
        for (int off = 32; off > 0; off >>= 1) ss += __shfl_xor(ss, off);
        int wave = tid >> 6, lane = tid & 63;
        if (lane == 0) wsum[wave] = ss;
        __syncthreads();
        ss = wsum[0] + wsum[1] + wsum[2];
        float scale = rsqrtf(ss * (1.f / 1536.f) + 1e-6f);
        short8 r8;
#pragma unroll
        for (int i = 0; i < 8; i++) r8[i] = (short)f2b(vf[i] * scale * g_qa[tid * 8 + i]);
        *(short8*)(qa + base) = r8;
    } else {
        int row = blk - 4096;
        if (tid < 64) {
            size_t base = (size_t)row * 576 + tid * 8;
            short8 v8 = *(const short8*)(ckv + base);
            float vf[8];
            float ss = 0.f;
#pragma unroll
            for (int i = 0; i < 8; i++) {
                vf[i] = b2f((unsigned short)v8[i]);
                ss += vf[i] * vf[i];
            }
            for (int off = 32; off > 0; off >>= 1) ss += __shfl_xor(ss, off);
            float scale = rsqrtf(ss * (1.f / 512.f) + 1e-6f);
            short8 r8;
#pragma unroll
            for (int i = 0; i < 8; i++) r8[i] = (short)f2b(vf[i] * scale * g_kva[tid * 8 + i]);
            *(short8*)(ckv + base) = r8;
        } else if (tid < 96) {
            int d = tid - 64;
            int s = row & 2047;
            size_t base = (size_t)row * 576 + 512;
            float inv = exp2f((float)d * -0.4152410118609203f);
            float f = (float)s * inv;
            float c, sn;
            sincosf(f, &sn, &c);
            float x1 = b2f(ckv[base + d]), x2 = b2f(ckv[base + d + 32]);
            ckv[base + d] = f2b(x1 * c - x2 * sn);
            ckv[base + d + 32] = f2b(x2 * c + x1 * sn);
        }
    }
}

// ---------------- Flash attention v10 = v9 + heavy-blocks-first ordering ----------------
// v9 counters: Occupancy 13.9% = ~4.45 waves/CU avg vs 8 at 2 blocks/CU.
// Theory: light blocks (qt 0..7) dispatched first finish early; heavy blocks
// (18-32 ktiles) then run ~1/CU with no co-resident partner. Heavy-first keeps
// pair-sums at 34 if scheduler pairs i/i+256 (no downside), and gives heavy
// blocks the full co-residency window if it fills in order (upside).
__global__ __launch_bounds__(256, 2)
void k_attn10(const unsigned short* __restrict__ q,    // [4096,3072] prescaled, NOT roped
              const unsigned short* __restrict__ kv,   // [4096,4096] k_nope (V cols unused)
              const unsigned short* __restrict__ ckv,  // [4096,576] cols 512.. roped k_pe
              const unsigned short* __restrict__ vt,   // [32][128][2048]
              unsigned short* __restrict__ ao)         // [4096,2048]
{
    __shared__ __align__(16) unsigned short Ks[2][12288];  // 2 x 24KB dbuf, [ks][64][32]
    __shared__ __align__(16) unsigned short Vs[8192];      // 16KB, [ks2][128][32]
    __shared__ __align__(16) unsigned short Pl[4][1280];   // per-wave P half, 32 rows x 40

    const int lb = blockIdx.x;
    const int qt = (lb < 256) ? (15 - (lb >> 5)) : ((lb & 255) >> 5);  // heavy first
    const int bh = lb & 31;
    const int b = bh >> 4, h = bh & 15;
    const int tid = threadIdx.x, wave = tid >> 6, lane = tid & 63;
    const int lrow = lane & 15, quad = lane >> 4;
    const int srow = lane >> 2, spiece = lane & 3;
    const int tok0 = b * 2048 + qt * 128;
    unsigned short* Pw = Pl[wave];

    // swizzle offsets: write-side (global source col) and read-side (slot)
    const int colx = spiece ^ ((srow >> 1) & 3);           // stage source column
    const int qx = (quad ^ ((lrow >> 1) & 3)) * 8;         // swizzled read slot (shorts)

    // Q fragments (B-operand: n=lane&15=qrow, k=quad*8+j); fused RoPE on ks=4,5
    short8 qf[2][6];
#pragma unroll
    for (int mi = 0; mi < 2; mi++) {
        int row = wave * 32 + mi * 16 + lrow;
        const unsigned short* qp = q + (size_t)(tok0 + row) * 3072 + h * 192;
#pragma unroll
        for (int ks = 0; ks < 6; ks++) qf[mi][ks] = *(const short8*)(qp + ks * 32 + quad * 8);
        float sp = (float)(qt * 128 + row);
#pragma unroll
        for (int j = 0; j < 8; j++) {
            float inv = exp2f((float)(quad * 8 + j) * -0.4152410118609203f);
            float f = sp * inv;
            float c, sn;
            sincosf(f, &sn, &c);
            float x1 = b2f((unsigned short)qf[mi][4][j]);
            float x2 = b2f((unsigned short)qf[mi][5][j]);
            qf[mi][4][j] = (short)f2b(x1 * c - x2 * sn);
            qf[mi][5][j] = (short)f2b(x2 * c + x1 * sn);
        }
    }

    short8 ones;
#pragma unroll
    for (int j = 0; j < 8; j++) ones[j] = (short)0x3F80;  // bf16 1.0

    float m_st[2];
    m_st[0] = m_st[1] = -__builtin_inff();
    float4v z4 = {0.f, 0.f, 0.f, 0.f};
    float4v o[2][8], osum[2];
#pragma unroll
    for (int mi = 0; mi < 2; mi++) {
        osum[mi] = z4;
#pragma unroll
        for (int dt = 0; dt < 8; dt++) o[mi][dt] = z4;
    }

    const int nk = 2 * qt + 2;

    auto stageK = [&](int kt, int buf) {
        const int kb = kt * 64;
#pragma unroll
        for (int ii = 0; ii < 6; ++ii) {
            int id = wave * 6 + ii;
            int ks = id >> 2;
            int row = (id & 3) * 16 + srow;
            int key = b * 2048 + kb + row;
            const unsigned short* g =
                (ks < 4) ? kv + (size_t)key * 4096 + h * 256 + ks * 32 + colx * 8
                         : ckv + (size_t)key * 576 + 512 + (ks - 4) * 32 + colx * 8;
            async16(&Ks[buf][id * 512], g);
        }
    };
    auto stageV = [&](int kt) {
        const int kb = kt * 64;
#pragma unroll
        for (int ii = 0; ii < 4; ++ii) {
            int id = wave * 4 + ii;
            int d = (id & 7) * 16 + srow;
            const unsigned short* g =
                vt + ((size_t)bh * 128 + d) * 2048 + kb + (id >> 3) * 32 + colx * 8;
            async16(&Vs[id * 512], g);
        }
    };

    stageK(0, 0);

    for (int kt = 0; kt < nk; ++kt) {
        __syncthreads();  // K(kt) ready; Vs safe to overwrite (prev PV done)
        stageV(kt);                       // consumed after mid barrier
        if (kt + 1 < nk) stageK(kt + 1, (kt + 1) & 1);
        const unsigned short* Kb = Ks[kt & 1];
        const int kb = kt * 64;

        // ---- S^T = K·Q^T (exp2 domain) ----
        float4v sc[2][4];
#pragma unroll
        for (int mi = 0; mi < 2; mi++)
#pragma unroll
            for (int nt = 0; nt < 4; nt++) sc[mi][nt] = z4;
        __builtin_amdgcn_s_setprio(1);
#pragma unroll
        for (int ks = 0; ks < 6; ks++) {
#pragma unroll
            for (int nt = 0; nt < 4; nt++) {
                short8 kf = *(const short8*)&Kb[ks * 2048 + nt * 512 + lrow * 32 + qx];
                sc[0][nt] = __builtin_amdgcn_mfma_f32_16x16x32_bf16(kf, qf[0][ks], sc[0][nt], 0, 0, 0);
                sc[1][nt] = __builtin_amdgcn_mfma_f32_16x16x32_bf16(kf, qf[1][ks], sc[1][nt], 0, 0, 0);
            }
        }
        __builtin_amdgcn_s_setprio(0);

        // ---- causal mask (diagonal 128 only) ----
        if (kt >= nk - 2) {
#pragma unroll
            for (int mi = 0; mi < 2; mi++) {
                int rowc = qt * 128 + wave * 32 + mi * 16 + lrow;
#pragma unroll
                for (int nt = 0; nt < 4; nt++)
#pragma unroll
                    for (int r = 0; r < 4; r++) {
                        int keyc = kb + nt * 16 + quad * 4 + r;
                        if (keyc > rowc) sc[mi][nt][r] = -__builtin_inff();
                    }
            }
        }

        // ---- online softmax: row max + T13 defer-max ----
        float mx[2];
#pragma unroll
        for (int mi = 0; mi < 2; mi++) {
            float m = sc[mi][0][0];
#pragma unroll
            for (int nt = 0; nt < 4; nt++)
#pragma unroll
                for (int r = 0; r < 4; r++) m = fmaxf(m, sc[mi][nt][r]);
            m = fmaxf(m, __shfl_xor(m, 16));
            m = fmaxf(m, __shfl_xor(m, 32));
            mx[mi] = m;
        }
        bool within = (mx[0] <= m_st[0] + 6.f) && (mx[1] <= m_st[1] + 6.f);
        if (!__all(within)) {
            float alpha[2];
#pragma unroll
            for (int mi = 0; mi < 2; mi++) {
                float mnew = fmaxf(m_st[mi], mx[mi]);
                alpha[mi] = exp2f(m_st[mi] - mnew);
                m_st[mi] = mnew;
            }
            float arow[2][4];
#pragma unroll
            for (int mi = 0; mi < 2; mi++)
#pragma unroll
                for (int r = 0; r < 4; r++) arow[mi][r] = __shfl(alpha[mi], quad * 4 + r);
#pragma unroll
            for (int mi = 0; mi < 2; mi++) {
#pragma unroll
                for (int r = 0; r < 4; r++) osum[mi][r] *= arow[mi][r];
#pragma unroll
                for (int dt = 0; dt < 8; dt++)
#pragma unroll
                    for (int r = 0; r < 4; r++) o[mi][dt][r] *= arow[mi][r];
            }
        }
        uint2v pk[2][4];
#pragma unroll
        for (int mi = 0; mi < 2; mi++) {
#pragma unroll
            for (int nt = 0; nt < 4; nt++) {
                float p0 = exp2f(sc[mi][nt][0] - m_st[mi]);
                float p1 = exp2f(sc[mi][nt][1] - m_st[mi]);
                float p2 = exp2f(sc[mi][nt][2] - m_st[mi]);
                float p3 = exp2f(sc[mi][nt][3] - m_st[mi]);
                pk[mi][nt].x = (unsigned int)f2b(p0) | ((unsigned int)f2b(p1) << 16);
                pk[mi][nt].y = (unsigned int)f2b(p2) | ((unsigned int)f2b(p3) << 16);
            }
        }

        __syncthreads();  // V(kt) DMA complete (cross-wave) — overlapped w/ QK+softmax

        // ---- PV in two 32-key halves through the per-wave P buffer ----
#pragma unroll
        for (int ks2 = 0; ks2 < 2; ks2++) {
#pragma unroll
            for (int mi = 0; mi < 2; mi++) {
                int row = mi * 16 + lrow;
                *(uint2v*)&Pw[row * 40 + quad * 4] = pk[mi][ks2 * 2];
                *(uint2v*)&Pw[row * 40 + 16 + quad * 4] = pk[mi][ks2 * 2 + 1];
            }
            short8 pa0 = *(const short8*)&Pw[lrow * 40 + quad * 8];
            short8 pa1 = *(const short8*)&Pw[(16 + lrow) * 40 + quad * 8];
            __builtin_amdgcn_s_setprio(1);
#pragma unroll
            for (int dt = 0; dt < 8; dt++) {
                short8 vf = *(const short8*)&Vs[(ks2 * 8 + dt) * 512 + lrow * 32 + qx];
                o[0][dt] = __builtin_amdgcn_mfma_f32_16x16x32_bf16(pa0, vf, o[0][dt], 0, 0, 0);
                o[1][dt] = __builtin_amdgcn_mfma_f32_16x16x32_bf16(pa1, vf, o[1][dt], 0, 0, 0);
            }
            osum[0] = __builtin_amdgcn_mfma_f32_16x16x32_bf16(pa0, ones, osum[0], 0, 0, 0);
            osum[1] = __builtin_amdgcn_mfma_f32_16x16x32_bf16(pa1, ones, osum[1], 0, 0, 0);
            __builtin_amdgcn_s_setprio(0);
        }
    }

    // ---- finalize: O /= l (l per-lane via osum), store ----
#pragma unroll
    for (int mi = 0; mi < 2; mi++) {
#pragma unroll
        for (int r = 0; r < 4; r++) {
            float linv = 1.f / osum[mi][r];
            unsigned short* dst =
                ao + (size_t)(tok0 + wave * 32 + mi * 16 + quad * 4 + r) * 2048 + h * 128;
#pragma unroll
            for (int dt = 0; dt < 8; dt++) dst[dt * 16 + lrow] = f2b(o[mi][dt][r] * linv);
        }
    }
}

extern "C" void kernel_launch(void* const* d_in, const int* in_sizes, int n_in,
                              void* d_out, int out_size, void* d_ws, size_t ws_size,
                              hipStream_t stream) {
    (void)in_sizes; (void)n_in; (void)out_size; (void)ws_size;
    const float* hs    = (const float*)d_in[0];
    const float* w_qa  = (const float*)d_in[1];
    const float* g_qa  = (const float*)d_in[2];
    const float* w_qb  = (const float*)d_in[3];
    const float* w_kva = (const float*)d_in[4];
    const float* g_kva = (const float*)d_in[5];
    const float* w_kvb = (const float*)d_in[6];
    const float* w_o   = (const float*)d_in[7];

    char* ws = (char*)d_ws;
    size_t off = 0;
    auto alloc = [&](size_t bytes) -> unsigned short* {
        unsigned short* p = (unsigned short*)(ws + off);
        off += (bytes + 255) & ~(size_t)255;
        return p;
    };
    unsigned short* hb    = alloc(4096ull * 2048 * 2);
    unsigned short* wqa   = alloc(1536ull * 2048 * 2);
    unsigned short* wqb   = alloc(3072ull * 1536 * 2);
    unsigned short* wkva  = alloc(576ull * 2048 * 2);
    unsigned short* wkvb  = alloc(4096ull * 512 * 2);
    unsigned short* wo    = alloc(2048ull * 2048 * 2);
    unsigned short* qa    = alloc(4096ull * 1536 * 2);
    unsigned short* ckv   = alloc(4096ull * 576 * 2);
    unsigned short* qbuf  = alloc(4096ull * 3072 * 2);
    unsigned short* kvbuf = alloc(4096ull * 4096 * 2);
    unsigned short* vtb   = alloc(32ull * 128 * 2048 * 2);
    unsigned short* ao    = alloc(4096ull * 2048 * 2);

    // fold softmax scale * log2(e) into w_qb (RoPE is linear -> commutes)
    const float qscale = 0.07216878364870323f * 1.4426950408889634f;

    // single fused conversion dispatch (6 regions)
    k_f2b6<<<dim3(23168), dim3(256), 0, stream>>>(
        hs, hb, w_qa, wqa, w_qb, wqb, w_kva, wkva, w_kvb, wkvb, w_o, wo, qscale);

    // ganged: qa GEMM (12 col-blocks) + ckv GEMM (5 col-blocks), both A=hb K=2048
    k_gemm_dual<<<dim3(17, 32), 256, 0, stream>>>(
        hb, 2048, wqa, qa, 1536, 1536, 2048, 12,
        hb, 2048, wkva, ckv, 576, 576, 2048, 0, nullptr);

    // fused rmsnorm(qa) + rmsnorm(ckv) + rope_k
    k_norm2<<<dim3(8192), dim3(192), 0, stream>>>(qa, g_qa, ckv, g_kva);

    // ganged: qb GEMM (24 col-blocks, K=1536) + kvb GEMM (32 col-blocks, K=512,
    // kvsplit epilogue writes V columns directly to vtb -> transpose kernel gone)
    k_gemm_dual<<<dim3(56, 32), 256, 0, stream>>>(
        qa, 1536, wqb, qbuf, 3072, 3072, 1536, 24,
        ckv, 576, wkvb, kvbuf, 4096, 4096, 512, 2, vtb);

    k_attn10<<<dim3(512), 256, 0, stream>>>(qbuf, kvbuf, ckv, vtb, ao);
    k_gemm_bt<<<dim3(16, 32), 256, 0, stream>>>(ao, 2048, wo, d_out, 2048, 2048, 2048, 1);
}

// Round 7
// 432.624 us; speedup vs baseline: 1.0738x; 1.0738x over previous
//
#include <hip/hip_runtime.h>
#include <cstdint>
#include <cstring>

typedef short short8 __attribute__((ext_vector_type(8)));
typedef float float4v __attribute__((ext_vector_type(4)));
typedef float float4g __attribute__((ext_vector_type(4)));
typedef unsigned short ushort4v __attribute__((ext_vector_type(4)));
typedef unsigned int uint2v __attribute__((ext_vector_type(2)));

typedef __attribute__((address_space(3))) unsigned int lds_uint;
typedef __attribute__((address_space(1))) const unsigned int glob_uint;

static __device__ __forceinline__ void async16(void* lds, const void* g) {
    __builtin_amdgcn_global_load_lds((glob_uint*)g, (lds_uint*)lds, 16, 0, 0);
}

static __device__ __forceinline__ float b2f(unsigned short u) {
    unsigned int x = ((unsigned int)u) << 16;
    float f;
    __builtin_memcpy(&f, &x, 4);
    return f;
}
static __device__ __forceinline__ unsigned short f2b(float f) {
    unsigned int x;
    __builtin_memcpy(&x, &f, 4);
    unsigned int r = (x + 0x7fffu + ((x >> 16) & 1u)) >> 16;
    return (unsigned short)r;
}

// ---------------- fused fp32 -> bf16 convert for all 6 tensors ----------------
// region block boundaries (each block = 1024 elems = 256 thr x 4):
// hs 8192 | wqa 3072 | wqb 4608 (scaled) | wkva 1152 | wkvb 2048 | wo 4096 => 23168
__global__ __launch_bounds__(256) void k_f2b6(
    const float* __restrict__ s0, unsigned short* __restrict__ d0,
    const float* __restrict__ s1, unsigned short* __restrict__ d1,
    const float* __restrict__ s2, unsigned short* __restrict__ d2,
    const float* __restrict__ s3, unsigned short* __restrict__ d3,
    const float* __restrict__ s4, unsigned short* __restrict__ d4,
    const float* __restrict__ s5, unsigned short* __restrict__ d5,
    float qs) {
    int blk = blockIdx.x;
    const float* s; unsigned short* d; float sc = 1.f; int rel;
    if (blk < 8192)       { s = s0; d = d0; rel = blk; }
    else if (blk < 11264) { s = s1; d = d1; rel = blk - 8192; }
    else if (blk < 15872) { s = s2; d = d2; rel = blk - 11264; sc = qs; }
    else if (blk < 17024) { s = s3; d = d3; rel = blk - 15872; }
    else if (blk < 19072) { s = s4; d = d4; rel = blk - 17024; }
    else                  { s = s5; d = d5; rel = blk - 19072; }
    int i = (rel * 256 + threadIdx.x) * 4;
    float4g v = *(const float4g*)(s + i);
    ushort4v r;
    r.x = f2b(v.x * sc); r.y = f2b(v.y * sc); r.z = f2b(v.z * sc); r.w = f2b(v.w * sc);
    *(ushort4v*)(d + i) = r;
}

// ---------------- bf16 GEMM body (m97 recipe): C[M,N] = A[M,K] @ W[N,K]^T ----------------
// mode: 0 = bf16 C, 1 = fp32 C, 2 = kvsplit (bf16 C for k_nope cols, V cols -> VT[bh][d][s])
static __device__ __forceinline__ void gemm_bt_body(
    const unsigned short* __restrict__ A, int lda,
    const unsigned short* __restrict__ W,
    void* __restrict__ C, int ldc,
    int N, int K, int mode, int bx, int by,
    unsigned short* __restrict__ VT) {
    __shared__ __align__(16) unsigned short As[128 * 32];
    __shared__ __align__(16) unsigned short Ws[128 * 32];
    const int tid = threadIdx.x;
    const int m0 = by * 128, n0 = bx * 128;
    const int wave = tid >> 6, lane = tid & 63;
    const int wm = (wave >> 1) * 64, wn = (wave & 1) * 64;
    const int lrow = lane & 15, quad = lane >> 4;
    const int srow = lane >> 2, spiece = lane & 3;

    float4v acc[4][4];
    float4v z = {0.f, 0.f, 0.f, 0.f};
#pragma unroll
    for (int i = 0; i < 4; i++)
#pragma unroll
        for (int j = 0; j < 4; j++) acc[i][j] = z;

    for (int k0 = 0; k0 < K; k0 += 32) {
#pragma unroll
        for (int ii = 0; ii < 2; ++ii) {
            int i = wave + ii * 4;
            int row = i * 16 + srow;
            async16(&As[i * 512], &A[(size_t)(m0 + row) * lda + k0 + spiece * 8]);
            int wr = n0 + row;
            if (wr > N - 1) wr = N - 1;
            async16(&Ws[i * 512], &W[(size_t)wr * K + k0 + spiece * 8]);
        }
        __syncthreads();
        short8 af[4], bfr[4];
#pragma unroll
        for (int i = 0; i < 4; i++)
            af[i] = *(const short8*)&As[(wm + i * 16 + lrow) * 32 + quad * 8];
#pragma unroll
        for (int i = 0; i < 4; i++)
            bfr[i] = *(const short8*)&Ws[(wn + i * 16 + lrow) * 32 + quad * 8];
#pragma unroll
        for (int i = 0; i < 4; i++)
#pragma unroll
            for (int j = 0; j < 4; j++)
                acc[i][j] = __builtin_amdgcn_mfma_f32_16x16x32_bf16(af[i], bfr[j], acc[i][j], 0, 0, 0);
        __syncthreads();
    }

    const int rbase = quad * 4;
#pragma unroll
    for (int i = 0; i < 4; i++) {
#pragma unroll
        for (int j = 0; j < 4; j++) {
            int col = n0 + wn + j * 16 + lrow;
            if (col >= N) continue;
            if (mode == 2) {
                // kvb output: col = h*256 + dd. dd<128 -> k_nope (kvbuf);
                // dd>=128 -> V, packed 8B store to VT[(b*16+h)][dd-128][s0..s0+3]
                // (rbase+r are 4 CONSECUTIVE tokens; batch boundary not crossed).
                int dd = col & 255, h = col >> 8;
                int row0 = m0 + wm + i * 16 + rbase;
                if (dd < 128) {
#pragma unroll
                    for (int r = 0; r < 4; r++)
                        ((unsigned short*)C)[(size_t)(row0 + r) * ldc + col] = f2b(acc[i][j][r]);
                } else {
                    int b = row0 >> 11, s0 = row0 & 2047;
                    ushort4v pv;
                    pv.x = f2b(acc[i][j][0]); pv.y = f2b(acc[i][j][1]);
                    pv.z = f2b(acc[i][j][2]); pv.w = f2b(acc[i][j][3]);
                    *(ushort4v*)&VT[((size_t)(b * 16 + h) * 128 + (dd - 128)) * 2048 + s0] = pv;
                }
            } else {
#pragma unroll
                for (int r = 0; r < 4; r++) {
                    int row = m0 + wm + i * 16 + rbase + r;
                    float v = acc[i][j][r];
                    if (mode == 1)
                        ((float*)C)[(size_t)row * ldc + col] = v;
                    else
                        ((unsigned short*)C)[(size_t)row * ldc + col] = f2b(v);
                }
            }
        }
    }
}

__global__ __launch_bounds__(256, 3)
void k_gemm_bt(const unsigned short* __restrict__ A, int lda,
               const unsigned short* __restrict__ W,
               void* __restrict__ C, int ldc,
               int N, int K, int mode) {
    gemm_bt_body(A, lda, W, C, ldc, N, K, mode, blockIdx.x, blockIdx.y, nullptr);
}

// Ganged dual-GEMM: blocks [0,nbx0) run problem 0 (bf16 out), rest problem 1
// (mode1: 0=bf16, 2=kvsplit with VT).
__global__ __launch_bounds__(256, 3)
void k_gemm_dual(const unsigned short* __restrict__ A0, int lda0,
                 const unsigned short* __restrict__ W0, void* __restrict__ C0,
                 int ldc0, int N0, int K0, int nbx0,
                 const unsigned short* __restrict__ A1, int lda1,
                 const unsigned short* __restrict__ W1, void* __restrict__ C1,
                 int ldc1, int N1, int K1, int mode1,
                 unsigned short* __restrict__ VT) {
    int bx = blockIdx.x;
    if (bx < nbx0) {
        gemm_bt_body(A0, lda0, W0, C0, ldc0, N0, K0, 0, bx, blockIdx.y, nullptr);
    } else {
        gemm_bt_body(A1, lda1, W1, C1, ldc1, N1, K1, mode1, bx - nbx0, blockIdx.y, VT);
    }
}

// ---------------- fused: rmsnorm(qa) | rmsnorm(ckv)+rope_k ----------------
__global__ __launch_bounds__(192) void k_norm2(
    unsigned short* __restrict__ qa, const float* __restrict__ g_qa,
    unsigned short* __restrict__ ckv, const float* __restrict__ g_kva) {
    __shared__ float wsum[3];
    int blk = blockIdx.x;
    int tid = threadIdx.x;
    if (blk < 4096) {
        size_t base = (size_t)blk * 1536 + tid * 8;
        short8 v8 = *(const short8*)(qa + base);
        float vf[8];
        float ss = 0.f;
#pragma unroll
        for (int i = 0; i < 8; i++) {
            vf[i] = b2f((unsigned short)v8[i]);
            ss += vf[i] * vf[i];
        }
        for (int off = 32; off > 0; off >>= 1) ss += __shfl_xor(ss, off);
        int wave = tid >> 6, lane = tid & 63;
        if (lane == 0) wsum[wave] = ss;
        __syncthreads();
        ss = wsum[0] + wsum[1] + wsum[2];
        float scale = rsqrtf(ss * (1.f / 1536.f) + 1e-6f);
        short8 r8;
#pragma unroll
        for (int i = 0; i < 8; i++) r8[i] = (short)f2b(vf[i] * scale * g_qa[tid * 8 + i]);
        *(short8*)(qa + base) = r8;
    } else {
        int row = blk - 4096;
        if (tid < 64) {
            size_t base = (size_t)row * 576 + tid * 8;
            short8 v8 = *(const short8*)(ckv + base);
            float vf[8];
            float ss = 0.f;
#pragma unroll
            for (int i = 0; i < 8; i++) {
                vf[i] = b2f((unsigned short)v8[i]);
                ss += vf[i] * vf[i];
            }
            for (int off = 32; off > 0; off >>= 1) ss += __shfl_xor(ss, off);
            float scale = rsqrtf(ss * (1.f / 512.f) + 1e-6f);
            short8 r8;
#pragma unroll
            for (int i = 0; i < 8; i++) r8[i] = (short)f2b(vf[i] * scale * g_kva[tid * 8 + i]);
            *(short8*)(ckv + base) = r8;
        } else if (tid < 96) {
            int d = tid - 64;
            int s = row & 2047;
            size_t base = (size_t)row * 576 + 512;
            float inv = exp2f((float)d * -0.4152410118609203f);
            float f = (float)s * inv;
            float c, sn;
            sincosf(f, &sn, &c);
            float x1 = b2f(ckv[base + d]), x2 = b2f(ckv[base + d + 32]);
            ckv[base + d] = f2b(x1 * c - x2 * sn);
            ckv[base + d + 32] = f2b(x2 * c + x1 * sn);
        }
    }
}

// ---------------- Flash attention v11 = v9 structure/mapping (97us verified) ----------------
// Heavy-first mapping (v10) measured +31us with identical inputs & pair-sums ->
// v9's light-first order is empirically required. Do not change this mapping.
__global__ __launch_bounds__(256, 2)
void k_attn11(const unsigned short* __restrict__ q,    // [4096,3072] prescaled, NOT roped
              const unsigned short* __restrict__ kv,   // [4096,4096] k_nope (V cols unused)
              const unsigned short* __restrict__ ckv,  // [4096,576] cols 512.. roped k_pe
              const unsigned short* __restrict__ vt,   // [32][128][2048]
              unsigned short* __restrict__ ao)         // [4096,2048]
{
    __shared__ __align__(16) unsigned short Ks[2][12288];  // 2 x 24KB dbuf, [ks][64][32]
    __shared__ __align__(16) unsigned short Vs[8192];      // 16KB, [ks2][128][32]
    __shared__ __align__(16) unsigned short Pl[4][1280];   // per-wave P half, 32 rows x 40

    const int lb = blockIdx.x;
    const int qt = (lb < 256) ? (lb >> 5) : 15 - ((lb & 255) >> 5);  // v9 mapping
    const int bh = lb & 31;
    const int b = bh >> 4, h = bh & 15;
    const int tid = threadIdx.x, wave = tid >> 6, lane = tid & 63;
    const int lrow = lane & 15, quad = lane >> 4;
    const int srow = lane >> 2, spiece = lane & 3;
    const int tok0 = b * 2048 + qt * 128;
    unsigned short* Pw = Pl[wave];

    // swizzle offsets: write-side (global source col) and read-side (slot)
    const int colx = spiece ^ ((srow >> 1) & 3);           // stage source column
    const int qx = (quad ^ ((lrow >> 1) & 3)) * 8;         // swizzled read slot (shorts)

    // Q fragments (B-operand: n=lane&15=qrow, k=quad*8+j); fused RoPE on ks=4,5
    short8 qf[2][6];
#pragma unroll
    for (int mi = 0; mi < 2; mi++) {
        int row = wave * 32 + mi * 16 + lrow;
        const unsigned short* qp = q + (size_t)(tok0 + row) * 3072 + h * 192;
#pragma unroll
        for (int ks = 0; ks < 6; ks++) qf[mi][ks] = *(const short8*)(qp + ks * 32 + quad * 8);
        float sp = (float)(qt * 128 + row);
#pragma unroll
        for (int j = 0; j < 8; j++) {
            float inv = exp2f((float)(quad * 8 + j) * -0.4152410118609203f);
            float f = sp * inv;
            float c, sn;
            sincosf(f, &sn, &c);
            float x1 = b2f((unsigned short)qf[mi][4][j]);
            float x2 = b2f((unsigned short)qf[mi][5][j]);
            qf[mi][4][j] = (short)f2b(x1 * c - x2 * sn);
            qf[mi][5][j] = (short)f2b(x2 * c + x1 * sn);
        }
    }

    short8 ones;
#pragma unroll
    for (int j = 0; j < 8; j++) ones[j] = (short)0x3F80;  // bf16 1.0

    float m_st[2];
    m_st[0] = m_st[1] = -__builtin_inff();
    float4v z4 = {0.f, 0.f, 0.f, 0.f};
    float4v o[2][8], osum[2];
#pragma unroll
    for (int mi = 0; mi < 2; mi++) {
        osum[mi] = z4;
#pragma unroll
        for (int dt = 0; dt < 8; dt++) o[mi][dt] = z4;
    }

    const int nk = 2 * qt + 2;

    auto stageK = [&](int kt, int buf) {
        const int kb = kt * 64;
#pragma unroll
        for (int ii = 0; ii < 6; ++ii) {
            int id = wave * 6 + ii;
            int ks = id >> 2;
            int row = (id & 3) * 16 + srow;
            int key = b * 2048 + kb + row;
            const unsigned short* g =
                (ks < 4) ? kv + (size_t)key * 4096 + h * 256 + ks * 32 + colx * 8
                         : ckv + (size_t)key * 576 + 512 + (ks - 4) * 32 + colx * 8;
            async16(&Ks[buf][id * 512], g);
        }
    };
    auto stageV = [&](int kt) {
        const int kb = kt * 64;
#pragma unroll
        for (int ii = 0; ii < 4; ++ii) {
            int id = wave * 4 + ii;
            int d = (id & 7) * 16 + srow;
            const unsigned short* g =
                vt + ((size_t)bh * 128 + d) * 2048 + kb + (id >> 3) * 32 + colx * 8;
            async16(&Vs[id * 512], g);
        }
    };

    stageK(0, 0);

    for (int kt = 0; kt < nk; ++kt) {
        __syncthreads();  // K(kt) ready; Vs safe to overwrite (prev PV done)
        stageV(kt);                       // consumed after mid barrier
        if (kt + 1 < nk) stageK(kt + 1, (kt + 1) & 1);
        const unsigned short* Kb = Ks[kt & 1];
        const int kb = kt * 64;

        // ---- S^T = K·Q^T (exp2 domain) ----
        float4v sc[2][4];
#pragma unroll
        for (int mi = 0; mi < 2; mi++)
#pragma unroll
            for (int nt = 0; nt < 4; nt++) sc[mi][nt] = z4;
        __builtin_amdgcn_s_setprio(1);
#pragma unroll
        for (int ks = 0; ks < 6; ks++) {
#pragma unroll
            for (int nt = 0; nt < 4; nt++) {
                short8 kf = *(const short8*)&Kb[ks * 2048 + nt * 512 + lrow * 32 + qx];
                sc[0][nt] = __builtin_amdgcn_mfma_f32_16x16x32_bf16(kf, qf[0][ks], sc[0][nt], 0, 0, 0);
                sc[1][nt] = __builtin_amdgcn_mfma_f32_16x16x32_bf16(kf, qf[1][ks], sc[1][nt], 0, 0, 0);
            }
        }
        __builtin_amdgcn_s_setprio(0);

        // ---- causal mask (diagonal 128 only) ----
        if (kt >= nk - 2) {
#pragma unroll
            for (int mi = 0; mi < 2; mi++) {
                int rowc = qt * 128 + wave * 32 + mi * 16 + lrow;
#pragma unroll
                for (int nt = 0; nt < 4; nt++)
#pragma unroll
                    for (int r = 0; r < 4; r++) {
                        int keyc = kb + nt * 16 + quad * 4 + r;
                        if (keyc > rowc) sc[mi][nt][r] = -__builtin_inff();
                    }
            }
        }

        // ---- online softmax: row max + T13 defer-max ----
        float mx[2];
#pragma unroll
        for (int mi = 0; mi < 2; mi++) {
            float m = sc[mi][0][0];
#pragma unroll
            for (int nt = 0; nt < 4; nt++)
#pragma unroll
                for (int r = 0; r < 4; r++) m = fmaxf(m, sc[mi][nt][r]);
            m = fmaxf(m, __shfl_xor(m, 16));
            m = fmaxf(m, __shfl_xor(m, 32));
            mx[mi] = m;
        }
        bool within = (mx[0] <= m_st[0] + 6.f) && (mx[1] <= m_st[1] + 6.f);
        if (!__all(within)) {
            float alpha[2];
#pragma unroll
            for (int mi = 0; mi < 2; mi++) {
                float mnew = fmaxf(m_st[mi], mx[mi]);
                alpha[mi] = exp2f(m_st[mi] - mnew);
                m_st[mi] = mnew;
            }
            float arow[2][4];
#pragma unroll
            for (int mi = 0; mi < 2; mi++)
#pragma unroll
                for (int r = 0; r < 4; r++) arow[mi][r] = __shfl(alpha[mi], quad * 4 + r);
#pragma unroll
            for (int mi = 0; mi < 2; mi++) {
#pragma unroll
                for (int r = 0; r < 4; r++) osum[mi][r] *= arow[mi][r];
#pragma unroll
                for (int dt = 0; dt < 8; dt++)
#pragma unroll
                    for (int r = 0; r < 4; r++) o[mi][dt][r] *= arow[mi][r];
            }
        }
        uint2v pk[2][4];
#pragma unroll
        for (int mi = 0; mi < 2; mi++) {
#pragma unroll
            for (int nt = 0; nt < 4; nt++) {
                float p0 = exp2f(sc[mi][nt][0] - m_st[mi]);
                float p1 = exp2f(sc[mi][nt][1] - m_st[mi]);
                float p2 = exp2f(sc[mi][nt][2] - m_st[mi]);
                float p3 = exp2f(sc[mi][nt][3] - m_st[mi]);
                pk[mi][nt].x = (unsigned int)f2b(p0) | ((unsigned int)f2b(p1) << 16);
                pk[mi][nt].y = (unsigned int)f2b(p2) | ((unsigned int)f2b(p3) << 16);
            }
        }

        __syncthreads();  // V(kt) DMA complete (cross-wave) — overlapped w/ QK+softmax

        // ---- PV in two 32-key halves through the per-wave P buffer ----
#pragma unroll
        for (int ks2 = 0; ks2 < 2; ks2++) {
#pragma unroll
            for (int mi = 0; mi < 2; mi++) {
                int row = mi * 16 + lrow;
                *(uint2v*)&Pw[row * 40 + quad * 4] = pk[mi][ks2 * 2];
                *(uint2v*)&Pw[row * 40 + 16 + quad * 4] = pk[mi][ks2 * 2 + 1];
            }
            short8 pa0 = *(const short8*)&Pw[lrow * 40 + quad * 8];
            short8 pa1 = *(const short8*)&Pw[(16 + lrow) * 40 + quad * 8];
            __builtin_amdgcn_s_setprio(1);
#pragma unroll
            for (int dt = 0; dt < 8; dt++) {
                short8 vf = *(const short8*)&Vs[(ks2 * 8 + dt) * 512 + lrow * 32 + qx];
                o[0][dt] = __builtin_amdgcn_mfma_f32_16x16x32_bf16(pa0, vf, o[0][dt], 0, 0, 0);
                o[1][dt] = __builtin_amdgcn_mfma_f32_16x16x32_bf16(pa1, vf, o[1][dt], 0, 0, 0);
            }
            osum[0] = __builtin_amdgcn_mfma_f32_16x16x32_bf16(pa0, ones, osum[0], 0, 0, 0);
            osum[1] = __builtin_amdgcn_mfma_f32_16x16x32_bf16(pa1, ones, osum[1], 0, 0, 0);
            __builtin_amdgcn_s_setprio(0);
        }
    }

    // ---- finalize: O /= l (l per-lane via osum), store ----
#pragma unroll
    for (int mi = 0; mi < 2; mi++) {
#pragma unroll
        for (int r = 0; r < 4; r++) {
            float linv = 1.f / osum[mi][r];
            unsigned short* dst =
                ao + (size_t)(tok0 + wave * 32 + mi * 16 + quad * 4 + r) * 2048 + h * 128;
#pragma unroll
            for (int dt = 0; dt < 8; dt++) dst[dt * 16 + lrow] = f2b(o[mi][dt][r] * linv);
        }
    }
}

extern "C" void kernel_launch(void* const* d_in, const int* in_sizes, int n_in,
                              void* d_out, int out_size, void* d_ws, size_t ws_size,
                              hipStream_t stream) {
    (void)in_sizes; (void)n_in; (void)out_size; (void)ws_size;
    const float* hs    = (const float*)d_in[0];
    const float* w_qa  = (const float*)d_in[1];
    const float* g_qa  = (const float*)d_in[2];
    const float* w_qb  = (const float*)d_in[3];
    const float* w_kva = (const float*)d_in[4];
    const float* g_kva = (const float*)d_in[5];
    const float* w_kvb = (const float*)d_in[6];
    const float* w_o   = (const float*)d_in[7];

    char* ws = (char*)d_ws;
    size_t off = 0;
    auto alloc = [&](size_t bytes) -> unsigned short* {
        unsigned short* p = (unsigned short*)(ws + off);
        off += (bytes + 255) & ~(size_t)255;
        return p;
    };
    unsigned short* hb    = alloc(4096ull * 2048 * 2);
    unsigned short* wqa   = alloc(1536ull * 2048 * 2);
    unsigned short* wqb   = alloc(3072ull * 1536 * 2);
    unsigned short* wkva  = alloc(576ull * 2048 * 2);
    unsigned short* wkvb  = alloc(4096ull * 512 * 2);
    unsigned short* wo    = alloc(2048ull * 2048 * 2);
    unsigned short* qa    = alloc(4096ull * 1536 * 2);
    unsigned short* ckv   = alloc(4096ull * 576 * 2);
    unsigned short* qbuf  = alloc(4096ull * 3072 * 2);
    unsigned short* kvbuf = alloc(4096ull * 4096 * 2);
    unsigned short* vtb   = alloc(32ull * 128 * 2048 * 2);
    unsigned short* ao    = alloc(4096ull * 2048 * 2);

    // fold softmax scale * log2(e) into w_qb (RoPE is linear -> commutes)
    const float qscale = 0.07216878364870323f * 1.4426950408889634f;

    // single fused conversion dispatch (6 regions)
    k_f2b6<<<dim3(23168), dim3(256), 0, stream>>>(
        hs, hb, w_qa, wqa, w_qb, wqb, w_kva, wkva, w_kvb, wkvb, w_o, wo, qscale);

    // ganged: qa GEMM (12 col-blocks) + ckv GEMM (5 col-blocks), both A=hb K=2048
    k_gemm_dual<<<dim3(17, 32), 256, 0, stream>>>(
        hb, 2048, wqa, qa, 1536, 1536, 2048, 12,
        hb, 2048, wkva, ckv, 576, 576, 2048, 0, nullptr);

    // fused rmsnorm(qa) + rmsnorm(ckv) + rope_k
    k_norm2<<<dim3(8192), dim3(192), 0, stream>>>(qa, g_qa, ckv, g_kva);

    // ganged: qb GEMM (24 col-blocks, K=1536) + kvb GEMM (32 col-blocks, K=512,
    // kvsplit epilogue: packed 8B V stores direct to vtb; no transpose kernel)
    k_gemm_dual<<<dim3(56, 32), 256, 0, stream>>>(
        qa, 1536, wqb, qbuf, 3072, 3072, 1536, 24,
        ckv, 576, wkvb, kvbuf, 4096, 4096, 512, 2, vtb);

    k_attn11<<<dim3(512), 256, 0, stream>>>(qbuf, kvbuf, ckv, vtb, ao);
    k_gemm_bt<<<dim3(16, 32), 256, 0, stream>>>(ao, 2048, wo, d_out, 2048, 2048, 2048, 1);
}

// Round 8
// 431.686 us; speedup vs baseline: 1.0761x; 1.0022x over previous
//
#include <hip/hip_runtime.h>
#include <cstdint>
#include <cstring>

typedef short short8 __attribute__((ext_vector_type(8)));
typedef float float4v __attribute__((ext_vector_type(4)));
typedef float float4g __attribute__((ext_vector_type(4)));
typedef unsigned short ushort4v __attribute__((ext_vector_type(4)));
typedef unsigned int uint2v __attribute__((ext_vector_type(2)));

typedef __attribute__((address_space(3))) unsigned int lds_uint;
typedef __attribute__((address_space(1))) const unsigned int glob_uint;

static __device__ __forceinline__ void async16(void* lds, const void* g) {
    __builtin_amdgcn_global_load_lds((glob_uint*)g, (lds_uint*)lds, 16, 0, 0);
}

static __device__ __forceinline__ float b2f(unsigned short u) {
    unsigned int x = ((unsigned int)u) << 16;
    float f;
    __builtin_memcpy(&f, &x, 4);
    return f;
}
static __device__ __forceinline__ unsigned short f2b(float f) {
    unsigned int x;
    __builtin_memcpy(&x, &f, 4);
    unsigned int r = (x + 0x7fffu + ((x >> 16) & 1u)) >> 16;
    return (unsigned short)r;
}

// ---------------- fused fp32 -> bf16 convert for all 6 tensors ----------------
// region block boundaries (each block = 1024 elems = 256 thr x 4):
// hs 8192 | wqa 3072 | wqb 4608 (scaled) | wkva 1152 | wkvb 2048 | wo 4096 => 23168
__global__ __launch_bounds__(256) void k_f2b6(
    const float* __restrict__ s0, unsigned short* __restrict__ d0,
    const float* __restrict__ s1, unsigned short* __restrict__ d1,
    const float* __restrict__ s2, unsigned short* __restrict__ d2,
    const float* __restrict__ s3, unsigned short* __restrict__ d3,
    const float* __restrict__ s4, unsigned short* __restrict__ d4,
    const float* __restrict__ s5, unsigned short* __restrict__ d5,
    float qs) {
    int blk = blockIdx.x;
    const float* s; unsigned short* d; float sc = 1.f; int rel;
    if (blk < 8192)       { s = s0; d = d0; rel = blk; }
    else if (blk < 11264) { s = s1; d = d1; rel = blk - 8192; }
    else if (blk < 15872) { s = s2; d = d2; rel = blk - 11264; sc = qs; }
    else if (blk < 17024) { s = s3; d = d3; rel = blk - 15872; }
    else if (blk < 19072) { s = s4; d = d4; rel = blk - 17024; }
    else                  { s = s5; d = d5; rel = blk - 19072; }
    int i = (rel * 256 + threadIdx.x) * 4;
    float4g v = *(const float4g*)(s + i);
    ushort4v r;
    r.x = f2b(v.x * sc); r.y = f2b(v.y * sc); r.z = f2b(v.z * sc); r.w = f2b(v.w * sc);
    *(ushort4v*)(d + i) = r;
}

// ---------------- bf16 GEMM body, BK=64: C[M,N] = A[M,K] @ W[N,K]^T ----------------
// m97 recipe with BK 32->64: per-iteration barrier drain (~550cy fixed cost,
// m131-m141: not removable at source) amortized over 2x MFMA+staging.
// LDS 32KB/block keeps 3 blocks/CU (vs BK=128's 64KB -> 2/CU regression, m132).
// Fragments loaded per k-half so VGPR stays at m97 level.
// mode: 0 = bf16 C, 1 = fp32 C, 2 = kvsplit (bf16 C for k_nope cols, V cols -> VT[bh][d][s])
static __device__ __forceinline__ void gemm_bt_body(
    const unsigned short* __restrict__ A, int lda,
    const unsigned short* __restrict__ W,
    void* __restrict__ C, int ldc,
    int N, int K, int mode, int bx, int by,
    unsigned short* __restrict__ VT) {
    __shared__ __align__(16) unsigned short As[128 * 64];
    __shared__ __align__(16) unsigned short Ws[128 * 64];
    const int tid = threadIdx.x;
    const int m0 = by * 128, n0 = bx * 128;
    const int wave = tid >> 6, lane = tid & 63;
    const int wm = (wave >> 1) * 64, wn = (wave & 1) * 64;
    const int lrow = lane & 15, quad = lane >> 4;
    const int crow = lane >> 3, ccol = lane & 7;  // staging: 8 rows x 8 x 16B per chunk

    float4v acc[4][4];
    float4v z = {0.f, 0.f, 0.f, 0.f};
#pragma unroll
    for (int i = 0; i < 4; i++)
#pragma unroll
        for (int j = 0; j < 4; j++) acc[i][j] = z;

    for (int k0 = 0; k0 < K; k0 += 64) {
#pragma unroll
        for (int ii = 0; ii < 4; ++ii) {
            int c = wave * 4 + ii;         // chunk 0..15, wave-uniform
            int row = c * 8 + crow;
            async16(&As[c * 512], &A[(size_t)(m0 + row) * lda + k0 + ccol * 8]);
            int wr = n0 + row;
            if (wr > N - 1) wr = N - 1;
            async16(&Ws[c * 512], &W[(size_t)wr * K + k0 + ccol * 8]);
        }
        __syncthreads();
#pragma unroll
        for (int h = 0; h < 2; ++h) {
            short8 af[4], bfr[4];
#pragma unroll
            for (int i = 0; i < 4; i++)
                af[i] = *(const short8*)&As[(wm + i * 16 + lrow) * 64 + h * 32 + quad * 8];
#pragma unroll
            for (int i = 0; i < 4; i++)
                bfr[i] = *(const short8*)&Ws[(wn + i * 16 + lrow) * 64 + h * 32 + quad * 8];
#pragma unroll
            for (int i = 0; i < 4; i++)
#pragma unroll
                for (int j = 0; j < 4; j++)
                    acc[i][j] = __builtin_amdgcn_mfma_f32_16x16x32_bf16(af[i], bfr[j], acc[i][j], 0, 0, 0);
        }
        __syncthreads();
    }

    const int rbase = quad * 4;
#pragma unroll
    for (int i = 0; i < 4; i++) {
#pragma unroll
        for (int j = 0; j < 4; j++) {
            int col = n0 + wn + j * 16 + lrow;
            if (col >= N) continue;
            if (mode == 2) {
                // kvb output: col = h*256 + dd. dd<128 -> k_nope (kvbuf);
                // dd>=128 -> V, packed 8B store to VT[(b*16+h)][dd-128][s0..s0+3]
                int dd = col & 255, h = col >> 8;
                int row0 = m0 + wm + i * 16 + rbase;
                if (dd < 128) {
#pragma unroll
                    for (int r = 0; r < 4; r++)
                        ((unsigned short*)C)[(size_t)(row0 + r) * ldc + col] = f2b(acc[i][j][r]);
                } else {
                    int b = row0 >> 11, s0 = row0 & 2047;
                    ushort4v pv;
                    pv.x = f2b(acc[i][j][0]); pv.y = f2b(acc[i][j][1]);
                    pv.z = f2b(acc[i][j][2]); pv.w = f2b(acc[i][j][3]);
                    *(ushort4v*)&VT[((size_t)(b * 16 + h) * 128 + (dd - 128)) * 2048 + s0] = pv;
                }
            } else {
#pragma unroll
                for (int r = 0; r < 4; r++) {
                    int row = m0 + wm + i * 16 + rbase + r;
                    float v = acc[i][j][r];
                    if (mode == 1)
                        ((float*)C)[(size_t)row * ldc + col] = v;
                    else
                        ((unsigned short*)C)[(size_t)row * ldc + col] = f2b(v);
                }
            }
        }
    }
}

__global__ __launch_bounds__(256, 3)
void k_gemm_bt(const unsigned short* __restrict__ A, int lda,
               const unsigned short* __restrict__ W,
               void* __restrict__ C, int ldc,
               int N, int K, int mode) {
    gemm_bt_body(A, lda, W, C, ldc, N, K, mode, blockIdx.x, blockIdx.y, nullptr);
}

// Ganged dual-GEMM: blocks [0,nbx0) run problem 0 (bf16 out), rest problem 1
// (mode1: 0=bf16, 2=kvsplit with VT).
__global__ __launch_bounds__(256, 3)
void k_gemm_dual(const unsigned short* __restrict__ A0, int lda0,
                 const unsigned short* __restrict__ W0, void* __restrict__ C0,
                 int ldc0, int N0, int K0, int nbx0,
                 const unsigned short* __restrict__ A1, int lda1,
                 const unsigned short* __restrict__ W1, void* __restrict__ C1,
                 int ldc1, int N1, int K1, int mode1,
                 unsigned short* __restrict__ VT) {
    int bx = blockIdx.x;
    if (bx < nbx0) {
        gemm_bt_body(A0, lda0, W0, C0, ldc0, N0, K0, 0, bx, blockIdx.y, nullptr);
    } else {
        gemm_bt_body(A1, lda1, W1, C1, ldc1, N1, K1, mode1, bx - nbx0, blockIdx.y, VT);
    }
}

// ---------------- fused: rmsnorm(qa) | rmsnorm(ckv)+rope_k ----------------
__global__ __launch_bounds__(192) void k_norm2(
    unsigned short* __restrict__ qa, const float* __restrict__ g_qa,
    unsigned short* __restrict__ ckv, const float* __restrict__ g_kva) {
    __shared__ float wsum[3];
    int blk = blockIdx.x;
    int tid = threadIdx.x;
    if (blk < 4096) {
        size_t base = (size_t)blk * 1536 + tid * 8;
        short8 v8 = *(const short8*)(qa + base);
        float vf[8];
        float ss = 0.f;
#pragma unroll
        for (int i = 0; i < 8; i++) {
            vf[i] = b2f((unsigned short)v8[i]);
            ss += vf[i] * vf[i];
        }
        for (int off = 32; off > 0; off >>= 1) ss += __shfl_xor(ss, off);
        int wave = tid >> 6, lane = tid & 63;
        if (lane == 0) wsum[wave] = ss;
        __syncthreads();
        ss = wsum[0] + wsum[1] + wsum[2];
        float scale = rsqrtf(ss * (1.f / 1536.f) + 1e-6f);
        short8 r8;
#pragma unroll
        for (int i = 0; i < 8; i++) r8[i] = (short)f2b(vf[i] * scale * g_qa[tid * 8 + i]);
        *(short8*)(qa + base) = r8;
    } else {
        int row = blk - 4096;
        if (tid < 64) {
            size_t base = (size_t)row * 576 + tid * 8;
            short8 v8 = *(const short8*)(ckv + base);
            float vf[8];
            float ss = 0.f;
#pragma unroll
            for (int i = 0; i < 8; i++) {
                vf[i] = b2f((unsigned short)v8[i]);
                ss += vf[i] * vf[i];
            }
            for (int off = 32; off > 0; off >>= 1) ss += __shfl_xor(ss, off);
            float scale = rsqrtf(ss * (1.f / 512.f) + 1e-6f);
            short8 r8;
#pragma unroll
            for (int i = 0; i < 8; i++) r8[i] = (short)f2b(vf[i] * scale * g_kva[tid * 8 + i]);
            *(short8*)(ckv + base) = r8;
        } else if (tid < 96) {
            int d = tid - 64;
            int s = row & 2047;
            size_t base = (size_t)row * 576 + 512;
            float inv = exp2f((float)d * -0.4152410118609203f);
            float f = (float)s * inv;
            float c, sn;
            sincosf(f, &sn, &c);
            float x1 = b2f(ckv[base + d]), x2 = b2f(ckv[base + d + 32]);
            ckv[base + d] = f2b(x1 * c - x2 * sn);
            ckv[base + d + 32] = f2b(x2 * c + x1 * sn);
        }
    }
}

// ---------------- Flash attention v11 = v9 structure/mapping (97us verified) ----------------
// Heavy-first mapping (v10) measured +31us with identical inputs & pair-sums ->
// v9's light-first order is empirically required. Do not change this mapping.
__global__ __launch_bounds__(256, 2)
void k_attn11(const unsigned short* __restrict__ q,    // [4096,3072] prescaled, NOT roped
              const unsigned short* __restrict__ kv,   // [4096,4096] k_nope (V cols unused)
              const unsigned short* __restrict__ ckv,  // [4096,576] cols 512.. roped k_pe
              const unsigned short* __restrict__ vt,   // [32][128][2048]
              unsigned short* __restrict__ ao)         // [4096,2048]
{
    __shared__ __align__(16) unsigned short Ks[2][12288];  // 2 x 24KB dbuf, [ks][64][32]
    __shared__ __align__(16) unsigned short Vs[8192];      // 16KB, [ks2][128][32]
    __shared__ __align__(16) unsigned short Pl[4][1280];   // per-wave P half, 32 rows x 40

    const int lb = blockIdx.x;
    const int qt = (lb < 256) ? (lb >> 5) : 15 - ((lb & 255) >> 5);  // v9 mapping
    const int bh = lb & 31;
    const int b = bh >> 4, h = bh & 15;
    const int tid = threadIdx.x, wave = tid >> 6, lane = tid & 63;
    const int lrow = lane & 15, quad = lane >> 4;
    const int srow = lane >> 2, spiece = lane & 3;
    const int tok0 = b * 2048 + qt * 128;
    unsigned short* Pw = Pl[wave];

    // swizzle offsets: write-side (global source col) and read-side (slot)
    const int colx = spiece ^ ((srow >> 1) & 3);           // stage source column
    const int qx = (quad ^ ((lrow >> 1) & 3)) * 8;         // swizzled read slot (shorts)

    // Q fragments (B-operand: n=lane&15=qrow, k=quad*8+j); fused RoPE on ks=4,5
    short8 qf[2][6];
#pragma unroll
    for (int mi = 0; mi < 2; mi++) {
        int row = wave * 32 + mi * 16 + lrow;
        const unsigned short* qp = q + (size_t)(tok0 + row) * 3072 + h * 192;
#pragma unroll
        for (int ks = 0; ks < 6; ks++) qf[mi][ks] = *(const short8*)(qp + ks * 32 + quad * 8);
        float sp = (float)(qt * 128 + row);
#pragma unroll
        for (int j = 0; j < 8; j++) {
            float inv = exp2f((float)(quad * 8 + j) * -0.4152410118609203f);
            float f = sp * inv;
            float c, sn;
            sincosf(f, &sn, &c);
            float x1 = b2f((unsigned short)qf[mi][4][j]);
            float x2 = b2f((unsigned short)qf[mi][5][j]);
            qf[mi][4][j] = (short)f2b(x1 * c - x2 * sn);
            qf[mi][5][j] = (short)f2b(x2 * c + x1 * sn);
        }
    }

    short8 ones;
#pragma unroll
    for (int j = 0; j < 8; j++) ones[j] = (short)0x3F80;  // bf16 1.0

    float m_st[2];
    m_st[0] = m_st[1] = -__builtin_inff();
    float4v z4 = {0.f, 0.f, 0.f, 0.f};
    float4v o[2][8], osum[2];
#pragma unroll
    for (int mi = 0; mi < 2; mi++) {
        osum[mi] = z4;
#pragma unroll
        for (int dt = 0; dt < 8; dt++) o[mi][dt] = z4;
    }

    const int nk = 2 * qt + 2;

    auto stageK = [&](int kt, int buf) {
        const int kb = kt * 64;
#pragma unroll
        for (int ii = 0; ii < 6; ++ii) {
            int id = wave * 6 + ii;
            int ks = id >> 2;
            int row = (id & 3) * 16 + srow;
            int key = b * 2048 + kb + row;
            const unsigned short* g =
                (ks < 4) ? kv + (size_t)key * 4096 + h * 256 + ks * 32 + colx * 8
                         : ckv + (size_t)key * 576 + 512 + (ks - 4) * 32 + colx * 8;
            async16(&Ks[buf][id * 512], g);
        }
    };
    auto stageV = [&](int kt) {
        const int kb = kt * 64;
#pragma unroll
        for (int ii = 0; ii < 4; ++ii) {
            int id = wave * 4 + ii;
            int d = (id & 7) * 16 + srow;
            const unsigned short* g =
                vt + ((size_t)bh * 128 + d) * 2048 + kb + (id >> 3) * 32 + colx * 8;
            async16(&Vs[id * 512], g);
        }
    };

    stageK(0, 0);

    for (int kt = 0; kt < nk; ++kt) {
        __syncthreads();  // K(kt) ready; Vs safe to overwrite (prev PV done)
        stageV(kt);                       // consumed after mid barrier
        if (kt + 1 < nk) stageK(kt + 1, (kt + 1) & 1);
        const unsigned short* Kb = Ks[kt & 1];
        const int kb = kt * 64;

        // ---- S^T = K·Q^T (exp2 domain) ----
        float4v sc[2][4];
#pragma unroll
        for (int mi = 0; mi < 2; mi++)
#pragma unroll
            for (int nt = 0; nt < 4; nt++) sc[mi][nt] = z4;
        __builtin_amdgcn_s_setprio(1);
#pragma unroll
        for (int ks = 0; ks < 6; ks++) {
#pragma unroll
            for (int nt = 0; nt < 4; nt++) {
                short8 kf = *(const short8*)&Kb[ks * 2048 + nt * 512 + lrow * 32 + qx];
                sc[0][nt] = __builtin_amdgcn_mfma_f32_16x16x32_bf16(kf, qf[0][ks], sc[0][nt], 0, 0, 0);
                sc[1][nt] = __builtin_amdgcn_mfma_f32_16x16x32_bf16(kf, qf[1][ks], sc[1][nt], 0, 0, 0);
            }
        }
        __builtin_amdgcn_s_setprio(0);

        // ---- causal mask (diagonal 128 only) ----
        if (kt >= nk - 2) {
#pragma unroll
            for (int mi = 0; mi < 2; mi++) {
                int rowc = qt * 128 + wave * 32 + mi * 16 + lrow;
#pragma unroll
                for (int nt = 0; nt < 4; nt++)
#pragma unroll
                    for (int r = 0; r < 4; r++) {
                        int keyc = kb + nt * 16 + quad * 4 + r;
                        if (keyc > rowc) sc[mi][nt][r] = -__builtin_inff();
                    }
            }
        }

        // ---- online softmax: row max + T13 defer-max ----
        float mx[2];
#pragma unroll
        for (int mi = 0; mi < 2; mi++) {
            float m = sc[mi][0][0];
#pragma unroll
            for (int nt = 0; nt < 4; nt++)
#pragma unroll
                for (int r = 0; r < 4; r++) m = fmaxf(m, sc[mi][nt][r]);
            m = fmaxf(m, __shfl_xor(m, 16));
            m = fmaxf(m, __shfl_xor(m, 32));
            mx[mi] = m;
        }
        bool within = (mx[0] <= m_st[0] + 6.f) && (mx[1] <= m_st[1] + 6.f);
        if (!__all(within)) {
            float alpha[2];
#pragma unroll
            for (int mi = 0; mi < 2; mi++) {
                float mnew = fmaxf(m_st[mi], mx[mi]);
                alpha[mi] = exp2f(m_st[mi] - mnew);
                m_st[mi] = mnew;
            }
            float arow[2][4];
#pragma unroll
            for (int mi = 0; mi < 2; mi++)
#pragma unroll
                for (int r = 0; r < 4; r++) arow[mi][r] = __shfl(alpha[mi], quad * 4 + r);
#pragma unroll
            for (int mi = 0; mi < 2; mi++) {
#pragma unroll
                for (int r = 0; r < 4; r++) osum[mi][r] *= arow[mi][r];
#pragma unroll
                for (int dt = 0; dt < 8; dt++)
#pragma unroll
                    for (int r = 0; r < 4; r++) o[mi][dt][r] *= arow[mi][r];
            }
        }
        uint2v pk[2][4];
#pragma unroll
        for (int mi = 0; mi < 2; mi++) {
#pragma unroll
            for (int nt = 0; nt < 4; nt++) {
                float p0 = exp2f(sc[mi][nt][0] - m_st[mi]);
                float p1 = exp2f(sc[mi][nt][1] - m_st[mi]);
                float p2 = exp2f(sc[mi][nt][2] - m_st[mi]);
                float p3 = exp2f(sc[mi][nt][3] - m_st[mi]);
                pk[mi][nt].x = (unsigned int)f2b(p0) | ((unsigned int)f2b(p1) << 16);
                pk[mi][nt].y = (unsigned int)f2b(p2) | ((unsigned int)f2b(p3) << 16);
            }
        }

        __syncthreads();  // V(kt) DMA complete (cross-wave) — overlapped w/ QK+softmax

        // ---- PV in two 32-key halves through the per-wave P buffer ----
#pragma unroll
        for (int ks2 = 0; ks2 < 2; ks2++) {
#pragma unroll
            for (int mi = 0; mi < 2; mi++) {
                int row = mi * 16 + lrow;
                *(uint2v*)&Pw[row * 40 + quad * 4] = pk[mi][ks2 * 2];
                *(uint2v*)&Pw[row * 40 + 16 + quad * 4] = pk[mi][ks2 * 2 + 1];
            }
            short8 pa0 = *(const short8*)&Pw[lrow * 40 + quad * 8];
            short8 pa1 = *(const short8*)&Pw[(16 + lrow) * 40 + quad * 8];
            __builtin_amdgcn_s_setprio(1);
#pragma unroll
            for (int dt = 0; dt < 8; dt++) {
                short8 vf = *(const short8*)&Vs[(ks2 * 8 + dt) * 512 + lrow * 32 + qx];
                o[0][dt] = __builtin_amdgcn_mfma_f32_16x16x32_bf16(pa0, vf, o[0][dt], 0, 0, 0);
                o[1][dt] = __builtin_amdgcn_mfma_f32_16x16x32_bf16(pa1, vf, o[1][dt], 0, 0, 0);
            }
            osum[0] = __builtin_amdgcn_mfma_f32_16x16x32_bf16(pa0, ones, osum[0], 0, 0, 0);
            osum[1] = __builtin_amdgcn_mfma_f32_16x16x32_bf16(pa1, ones, osum[1], 0, 0, 0);
            __builtin_amdgcn_s_setprio(0);
        }
    }

    // ---- finalize: O /= l (l per-lane via osum), store ----
#pragma unroll
    for (int mi = 0; mi < 2; mi++) {
#pragma unroll
        for (int r = 0; r < 4; r++) {
            float linv = 1.f / osum[mi][r];
            unsigned short* dst =
                ao + (size_t)(tok0 + wave * 32 + mi * 16 + quad * 4 + r) * 2048 + h * 128;
#pragma unroll
            for (int dt = 0; dt < 8; dt++) dst[dt * 16 + lrow] = f2b(o[mi][dt][r] * linv);
        }
    }
}

extern "C" void kernel_launch(void* const* d_in, const int* in_sizes, int n_in,
                              void* d_out, int out_size, void* d_ws, size_t ws_size,
                              hipStream_t stream) {
    (void)in_sizes; (void)n_in; (void)out_size; (void)ws_size;
    const float* hs    = (const float*)d_in[0];
    const float* w_qa  = (const float*)d_in[1];
    const float* g_qa  = (const float*)d_in[2];
    const float* w_qb  = (const float*)d_in[3];
    const float* w_kva = (const float*)d_in[4];
    const float* g_kva = (const float*)d_in[5];
    const float* w_kvb = (const float*)d_in[6];
    const float* w_o   = (const float*)d_in[7];

    char* ws = (char*)d_ws;
    size_t off = 0;
    auto alloc = [&](size_t bytes) -> unsigned short* {
        unsigned short* p = (unsigned short*)(ws + off);
        off += (bytes + 255) & ~(size_t)255;
        return p;
    };
    unsigned short* hb    = alloc(4096ull * 2048 * 2);
    unsigned short* wqa   = alloc(1536ull * 2048 * 2);
    unsigned short* wqb   = alloc(3072ull * 1536 * 2);
    unsigned short* wkva  = alloc(576ull * 2048 * 2);
    unsigned short* wkvb  = alloc(4096ull * 512 * 2);
    unsigned short* wo    = alloc(2048ull * 2048 * 2);
    unsigned short* qa    = alloc(4096ull * 1536 * 2);
    unsigned short* ckv   = alloc(4096ull * 576 * 2);
    unsigned short* qbuf  = alloc(4096ull * 3072 * 2);
    unsigned short* kvbuf = alloc(4096ull * 4096 * 2);
    unsigned short* vtb   = alloc(32ull * 128 * 2048 * 2);
    unsigned short* ao    = alloc(4096ull * 2048 * 2);

    // fold softmax scale * log2(e) into w_qb (RoPE is linear -> commutes)
    const float qscale = 0.07216878364870323f * 1.4426950408889634f;

    // single fused conversion dispatch (6 regions)
    k_f2b6<<<dim3(23168), dim3(256), 0, stream>>>(
        hs, hb, w_qa, wqa, w_qb, wqb, w_kva, wkva, w_kvb, wkvb, w_o, wo, qscale);

    // ganged: qa GEMM (12 col-blocks) + ckv GEMM (5 col-blocks), both A=hb K=2048
    k_gemm_dual<<<dim3(17, 32), 256, 0, stream>>>(
        hb, 2048, wqa, qa, 1536, 1536, 2048, 12,
        hb, 2048, wkva, ckv, 576, 576, 2048, 0, nullptr);

    // fused rmsnorm(qa) + rmsnorm(ckv) + rope_k
    k_norm2<<<dim3(8192), dim3(192), 0, stream>>>(qa, g_qa, ckv, g_kva);

    // ganged: qb GEMM (24 col-blocks, K=1536) + kvb GEMM (32 col-blocks, K=512,
    // kvsplit epilogue: packed 8B V stores direct to vtb; no transpose kernel)
    k_gemm_dual<<<dim3(56, 32), 256, 0, stream>>>(
        qa, 1536, wqb, qbuf, 3072, 3072, 1536, 24,
        ckv, 576, wkvb, kvbuf, 4096, 4096, 512, 2, vtb);

    k_attn11<<<dim3(512), 256, 0, stream>>>(qbuf, kvbuf, ckv, vtb, ao);
    k_gemm_bt<<<dim3(16, 32), 256, 0, stream>>>(ao, 2048, wo, d_out, 2048, 2048, 2048, 1);
}